// Round 15
// baseline (35.077 us; speedup 1.0000x reference)
//
#include <hip/hip_runtime.h>

#define LSTREAM 512
#define C 8
#define OUTD 584    // 8 + 64 + 512
#define NW 16       // waves per block (segments per batch)
#define SEG 32      // increments per segment (last wave does 31)
#define INCF 4096   // inc buffer floats (511*8 rounded up, row 511 zeroed)
#define PSTRIDE 600 // partial-signature stride in floats
#define NREP 4      // DIAGNOSTIC: main loop repeated; main = (T - 15.4)/3

// Chen combine: state (a, in regs) <- a (x) b (in LDS at bp). a is earlier.
// Lane = i*8+j owns a2[i][j] (s2), a3[i][j][0..7] (s3); s1i = a1[i].
__device__ __forceinline__ void chen_combine(const float* bp, int i, int j, int lane,
                                             float& s1i, float& s2, float (&s3)[C]) {
    const float  b1i  = bp[i];
    const float  b1j  = bp[j];
    const float4 b1lo = *reinterpret_cast<const float4*>(bp);
    const float4 b1hi = *reinterpret_cast<const float4*>(bp + 4);
    const float4 b2lo = *reinterpret_cast<const float4*>(bp + C + j * C);
    const float4 b2hi = *reinterpret_cast<const float4*>(bp + C + j * C + 4);
    const float  b2ij = bp[C + lane];
    const float4 b3lo = *reinterpret_cast<const float4*>(bp + C + 64 + lane * C);
    const float4 b3hi = *reinterpret_cast<const float4*>(bp + C + 64 + lane * C + 4);
    const float b1k[C]  = {b1lo.x, b1lo.y, b1lo.z, b1lo.w, b1hi.x, b1hi.y, b1hi.z, b1hi.w};
    const float b2jk[C] = {b2lo.x, b2lo.y, b2lo.z, b2lo.w, b2hi.x, b2hi.y, b2hi.z, b2hi.w};
    const float b3k[C]  = {b3lo.x, b3lo.y, b3lo.z, b3lo.w, b3hi.x, b3hi.y, b3hi.z, b3hi.w};
    #pragma unroll
    for (int k = 0; k < C; ++k)
        s3[k] = s3[k] + b3k[k] + s1i * b2jk[k] + s2 * b1k[k];
    s2 = s2 + b2ij + s1i * b1j;
    s1i += b1i;
}

__device__ __forceinline__ void store_partial(float* pp, int i, int j, int lane,
                                              float s1i, float s2, const float (&s3)[C]) {
    if (j == 0) pp[i] = s1i;
    pp[C + lane] = s2;
    #pragma unroll
    for (int k = 0; k < C; ++k) pp[C + 64 + lane * C + k] = s3[k];
}

__global__ __launch_bounds__(1024, 8) void sig_kernel(const float* __restrict__ path,
                                                      float* __restrict__ out) {
    __shared__ float inc[INCF];            // 16 KB: increment rows 0..510, row 511 = 0
    __shared__ float part[NW * PSTRIDE];   // 37.5 KB: per-wave partial signatures
    const int b    = blockIdx.x;
    const int tid  = threadIdx.x;
    const int wu   = tid >> 6;
    const int lane = tid & 63;

    const float* p = path + (size_t)b * (LSTREAM * C);
    // ---- pre-pass: increments from global (coalesced); zero-pad row 511 ----
    {
        const int row = tid >> 1;
        float4 d = {0.f, 0.f, 0.f, 0.f};
        if (row < LSTREAM - 1) {
            const float4* p4 = reinterpret_cast<const float4*>(p);
            const float4 a = p4[tid];       // (row, half)
            const float4 c = p4[tid + 2];   // (row+1, half)
            d.x = c.x - a.x; d.y = c.y - a.y; d.z = c.z - a.z; d.w = c.w - a.w;
        }
        reinterpret_cast<float4*>(inc)[tid] = d;
    }
    __syncthreads();

    const int i = lane >> 3;
    const int j = lane & 7;

    const int r0 = wu * SEG;
    const int nst = min(SEG, (LSTREAM - 1) - r0);

    float s1i = 0.f, s2 = 0.f;
    float s3[C];

    // ---- DIAGNOSTIC rep loop: identical main-loop work NREP times ----
    #pragma unroll 1
    for (int rep = 0; rep < NREP; ++rep) {
        s1i = 0.f; s2 = 0.f;
        #pragma unroll
        for (int k = 0; k < C; ++k) s3[k] = 0.f;

        const float* ib = inc + r0 * C;
        #pragma unroll 4
        for (int t = 0; t < nst; ++t, ib += C) {
            const float4 a = *reinterpret_cast<const float4*>(ib);
            const float4 c = *reinterpret_cast<const float4*>(ib + 4);
            const float dx[C] = {a.x, a.y, a.z, a.w, c.x, c.y, c.z, c.w};
            const float dxi = ib[i];
            const float dxj = ib[j];

            const float u  = dxi * dxj;
            const float t1 = s1i * dxj;
            const float coeff = fmaf(u, (1.f / 6.f), fmaf(t1, 0.5f, s2));
            #pragma unroll
            for (int k = 0; k < C; ++k) s3[k] = fmaf(coeff, dx[k], s3[k]);
            s2 = fmaf(u, 0.5f, s2) + t1;
            s1i += dxi;
        }
        // keep this rep's results live so DCE can't delete reps 0..NREP-2
        asm volatile("" :: "v"(s1i), "v"(s2),
                     "v"(s3[0]), "v"(s3[1]), "v"(s3[2]), "v"(s3[3]),
                     "v"(s3[4]), "v"(s3[5]), "v"(s3[6]), "v"(s3[7]));
    }

    // ---- publish partials, tree-combine 16 -> 1 (once; state = last rep) ----
    store_partial(part + wu * PSTRIDE, i, j, lane, s1i, s2, s3);
    __syncthreads();

    if ((wu & 1) == 0) chen_combine(part + (wu + 1) * PSTRIDE, i, j, lane, s1i, s2, s3);
    if (wu == 2 || wu == 6 || wu == 10 || wu == 14)
        store_partial(part + wu * PSTRIDE, i, j, lane, s1i, s2, s3);
    __syncthreads();

    if ((wu & 3) == 0) chen_combine(part + (wu + 2) * PSTRIDE, i, j, lane, s1i, s2, s3);
    if (wu == 4 || wu == 12)
        store_partial(part + wu * PSTRIDE, i, j, lane, s1i, s2, s3);
    __syncthreads();

    if ((wu & 7) == 0) chen_combine(part + (wu + 4) * PSTRIDE, i, j, lane, s1i, s2, s3);
    if (wu == 8)
        store_partial(part + wu * PSTRIDE, i, j, lane, s1i, s2, s3);
    __syncthreads();

    if (wu == 0) {
        chen_combine(part + 8 * PSTRIDE, i, j, lane, s1i, s2, s3);
        float* ob = out + (size_t)b * OUTD;
        const float s1out = __shfl(s1i, (lane << 3) & 63, 64);
        if (lane < C) ob[lane] = s1out;
        ob[C + lane] = s2;
        #pragma unroll
        for (int k = 0; k < C; ++k) ob[C + 64 + lane * C + k] = s3[k];
    }
}

extern "C" void kernel_launch(void* const* d_in, const int* in_sizes, int n_in,
                              void* d_out, int out_size, void* d_ws, size_t ws_size,
                              hipStream_t stream) {
    const float* path = (const float*)d_in[0];
    float* out = (float*)d_out;
    const int B = in_sizes[0] / (LSTREAM * C);
    sig_kernel<<<B, 1024, 0, stream>>>(path, out);
}

// Round 16
// 15.404 us; speedup vs baseline: 2.2771x; 2.2771x over previous
//
#include <hip/hip_runtime.h>

#define LSTREAM 512
#define C 8
#define OUTD 584    // 8 + 64 + 512
#define NW 16       // waves per block (segments per batch)
#define SEG 32      // increments per segment (last wave does 31)
#define INCF 4096   // inc buffer floats (511*8 rounded up, row 511 zeroed)
#define PSTRIDE 600 // partial-signature stride in floats

typedef float f32x2 __attribute__((ext_vector_type(2)));

// Chen combine: state (a, in regs) <- a (x) b (in LDS at bp). a is earlier.
// Lane = i*8+j owns a2[i][j] (s2), a3[i][j][0..7] (s3); s1i = a1[i].
__device__ __forceinline__ void chen_combine(const float* bp, int i, int j, int lane,
                                             float& s1i, float& s2, float (&s3)[C]) {
    const float  b1i  = bp[i];
    const float  b1j  = bp[j];
    const float4 b1lo = *reinterpret_cast<const float4*>(bp);
    const float4 b1hi = *reinterpret_cast<const float4*>(bp + 4);
    const float4 b2lo = *reinterpret_cast<const float4*>(bp + C + j * C);
    const float4 b2hi = *reinterpret_cast<const float4*>(bp + C + j * C + 4);
    const float  b2ij = bp[C + lane];
    const float4 b3lo = *reinterpret_cast<const float4*>(bp + C + 64 + lane * C);
    const float4 b3hi = *reinterpret_cast<const float4*>(bp + C + 64 + lane * C + 4);
    const float b1k[C]  = {b1lo.x, b1lo.y, b1lo.z, b1lo.w, b1hi.x, b1hi.y, b1hi.z, b1hi.w};
    const float b2jk[C] = {b2lo.x, b2lo.y, b2lo.z, b2lo.w, b2hi.x, b2hi.y, b2hi.z, b2hi.w};
    const float b3k[C]  = {b3lo.x, b3lo.y, b3lo.z, b3lo.w, b3hi.x, b3hi.y, b3hi.z, b3hi.w};
    #pragma unroll
    for (int k = 0; k < C; ++k)
        s3[k] = s3[k] + b3k[k] + s1i * b2jk[k] + s2 * b1k[k];
    s2 = s2 + b2ij + s1i * b1j;
    s1i += b1i;
}

__device__ __forceinline__ void store_partial(float* pp, int i, int j, int lane,
                                              float s1i, float s2, const float (&s3)[C]) {
    if (j == 0) pp[i] = s1i;
    pp[C + lane] = s2;
    #pragma unroll
    for (int k = 0; k < C; ++k) pp[C + 64 + lane * C + k] = s3[k];
}

__global__ __launch_bounds__(1024, 8) void sig_kernel(const float* __restrict__ path,
                                                      float* __restrict__ out) {
    __shared__ float inc[INCF];            // 16 KB: increment rows 0..510, row 511 = 0
    __shared__ float part[NW * PSTRIDE];   // 37.5 KB: per-wave partial signatures
    const int b    = blockIdx.x;
    const int tid  = threadIdx.x;
    const int wu   = tid >> 6;
    const int lane = tid & 63;

    const float* p = path + (size_t)b * (LSTREAM * C);
    // ---- pre-pass: increments from global (coalesced); zero-pad row 511 ----
    {
        const int row = tid >> 1;
        float4 d = {0.f, 0.f, 0.f, 0.f};
        if (row < LSTREAM - 1) {
            const float4* p4 = reinterpret_cast<const float4*>(p);
            const float4 a = p4[tid];       // (row, half)
            const float4 c = p4[tid + 2];   // (row+1, half)
            d.x = c.x - a.x; d.y = c.y - a.y; d.z = c.z - a.z; d.w = c.w - a.w;
        }
        reinterpret_cast<float4*>(inc)[tid] = d;
    }
    __syncthreads();

    const int i = lane >> 3;
    const int j = lane & 7;

    const int r0 = wu * SEG;
    const int nst = min(SEG, (LSTREAM - 1) - r0);

    float s1i = 0.f, s2 = 0.f;
    // s3 as 4 float2 pairs -> v_pk_fma_f32 (2 FMAs/instr) in the hot loop
    f32x2 s3v[4];
    #pragma unroll
    for (int q = 0; q < 4; ++q) s3v[q] = (f32x2){0.f, 0.f};

    const float* ib = inc + r0 * C;
    #pragma unroll 4
    for (int t = 0; t < nst; ++t, ib += C) {
        const float4 a = *reinterpret_cast<const float4*>(ib);
        const float4 c = *reinterpret_cast<const float4*>(ib + 4);
        const float dxi = ib[i];
        const float dxj = ib[j];

        const float u  = dxi * dxj;
        const float t1 = s1i * dxj;
        const float coeff = fmaf(u, (1.f / 6.f), fmaf(t1, 0.5f, s2));
        const f32x2 cf2 = {coeff, coeff};
        s3v[0] = __builtin_elementwise_fma(cf2, (f32x2){a.x, a.y}, s3v[0]);
        s3v[1] = __builtin_elementwise_fma(cf2, (f32x2){a.z, a.w}, s3v[1]);
        s3v[2] = __builtin_elementwise_fma(cf2, (f32x2){c.x, c.y}, s3v[2]);
        s3v[3] = __builtin_elementwise_fma(cf2, (f32x2){c.z, c.w}, s3v[3]);
        s2 = fmaf(u, 0.5f, s2) + t1;
        s1i += dxi;
    }

    float s3[C] = {s3v[0].x, s3v[0].y, s3v[1].x, s3v[1].y,
                   s3v[2].x, s3v[2].y, s3v[3].x, s3v[3].y};

    // ---- publish partials, tree-combine 16 -> 1 ----
    store_partial(part + wu * PSTRIDE, i, j, lane, s1i, s2, s3);
    __syncthreads();

    if ((wu & 1) == 0) chen_combine(part + (wu + 1) * PSTRIDE, i, j, lane, s1i, s2, s3);
    if (wu == 2 || wu == 6 || wu == 10 || wu == 14)
        store_partial(part + wu * PSTRIDE, i, j, lane, s1i, s2, s3);
    __syncthreads();

    if ((wu & 3) == 0) chen_combine(part + (wu + 2) * PSTRIDE, i, j, lane, s1i, s2, s3);
    if (wu == 4 || wu == 12)
        store_partial(part + wu * PSTRIDE, i, j, lane, s1i, s2, s3);
    __syncthreads();

    if ((wu & 7) == 0) chen_combine(part + (wu + 4) * PSTRIDE, i, j, lane, s1i, s2, s3);
    if (wu == 8)
        store_partial(part + wu * PSTRIDE, i, j, lane, s1i, s2, s3);
    __syncthreads();

    if (wu == 0) {
        chen_combine(part + 8 * PSTRIDE, i, j, lane, s1i, s2, s3);
        float* ob = out + (size_t)b * OUTD;
        const float s1out = __shfl(s1i, (lane << 3) & 63, 64);
        if (lane < C) ob[lane] = s1out;
        ob[C + lane] = s2;
        #pragma unroll
        for (int k = 0; k < C; ++k) ob[C + 64 + lane * C + k] = s3[k];
    }
}

extern "C" void kernel_launch(void* const* d_in, const int* in_sizes, int n_in,
                              void* d_out, int out_size, void* d_ws, size_t ws_size,
                              hipStream_t stream) {
    const float* path = (const float*)d_in[0];
    float* out = (float*)d_out;
    const int B = in_sizes[0] / (LSTREAM * C);
    sig_kernel<<<B, 1024, 0, stream>>>(path, out);
}